// Round 2
// baseline (2474.524 us; speedup 1.0000x reference)
//
#include <hip/hip_runtime.h>
#include <cmath>

#define BB   8
#define NN   8192
#define DIMC 512
#define HH   8
#define DHD  64
#define HIDC 512
#define TCDC 512

// ---------------- K1: t = silu(time) @ w_time + b_time -> cs, ct ----------------
// cs[b,d] = ln_gamma[d] * (1 + t_scale[b,d]);  ct[b,d] = t_shift[b,d]
// grid (B, 2): block (b, half) computes 256 columns, one per thread.
__global__ __launch_bounds__(256) void k_time_mlp(
    const float* __restrict__ timev, const float* __restrict__ w_time,
    const float* __restrict__ b_time, const float* __restrict__ ln_gamma,
    float* __restrict__ cs, float* __restrict__ ct) {
  int b = blockIdx.x;
  int d = blockIdx.y * 256 + threadIdx.x;
  int tid = threadIdx.x;
  __shared__ float st[TCDC];
  for (int k = tid; k < TCDC; k += 256) {
    float v = timev[b * TCDC + k];
    st[k] = v / (1.f + __expf(-v));   // silu
  }
  __syncthreads();
  float accs = b_time[d];
  float acct = b_time[DIMC + d];
  for (int k = 0; k < TCDC; ++k) {
    float s = st[k];
    accs = fmaf(s, w_time[k * (2 * DIMC) + d], accs);
    acct = fmaf(s, w_time[k * (2 * DIMC) + DIMC + d], acct);
  }
  cs[b * DIMC + d] = ln_gamma[d] * (1.f + accs);
  ct[b * DIMC + d] = acct;
}

// ---------------- K2: per-row mean / rstd of x ----------------
__global__ __launch_bounds__(256) void k_rowstats(
    const float* __restrict__ x, float* __restrict__ mean, float* __restrict__ rstd) {
  int row = blockIdx.x * 4 + (threadIdx.x >> 6);
  int lane = threadIdx.x & 63;
  const float4* xr = (const float4*)(x + (size_t)row * DIMC);
  float s = 0.f, s2 = 0.f;
#pragma unroll
  for (int i = 0; i < 2; ++i) {
    float4 v = xr[lane + 64 * i];
    s  += v.x + v.y + v.z + v.w;
    s2 += v.x * v.x + v.y * v.y + v.z * v.z + v.w * v.w;
  }
#pragma unroll
  for (int m = 1; m < 64; m <<= 1) { s += __shfl_xor(s, m); s2 += __shfl_xor(s2, m); }
  float mu = s * (1.f / DIMC);
  float var = s2 * (1.f / DIMC) - mu * mu;
  if (lane == 0) { mean[row] = mu; rstd[row] = rsqrtf(var + 1e-5f); }
}

// ---------------- K3: fused (LN+mod) x @ w_qkv with q/k epilogue ----------------
// tile 128x128, BK=16, 256 threads, 8x8 per thread (4+4 split frags)
__global__ __launch_bounds__(256) void k_qkv_gemm(
    const float* __restrict__ x, const float* __restrict__ w_qkv,
    const float* __restrict__ mean, const float* __restrict__ rstd,
    const float* __restrict__ cs, const float* __restrict__ ct,
    const float* __restrict__ g_q, const float* __restrict__ g_k,
    float* __restrict__ qs, float* __restrict__ k_n, float* __restrict__ v_h) {
  __shared__ float As[16][128];
  __shared__ float Bs[16][128];
  int tid = threadIdx.x;
  int tx = tid & 15, ty = tid >> 4;
  int n0 = blockIdx.x * 128;
  int m0 = blockIdx.y * 128;
  int b = m0 >> 13;   // 8192 rows per batch, BM=128 divides evenly

  float acc[8][8];
#pragma unroll
  for (int i = 0; i < 8; ++i)
#pragma unroll
    for (int j = 0; j < 8; ++j) acc[i][j] = 0.f;

  int ar = tid >> 2;   // 0..63 (A stage row)
  int akc = tid & 3;   // 0..3  (A stage k-chunk of 4)
  int bkr = tid >> 5;  // 0..7  (B stage k row)
  int bc4 = tid & 31;  // 0..31 (B stage col float4)

  // row stats are k-invariant: hoist
  float mu0 = mean[m0 + ar],      rs0 = rstd[m0 + ar];
  float mu1 = mean[m0 + ar + 64], rs1 = rstd[m0 + ar + 64];

  for (int k0 = 0; k0 < DIMC; k0 += 16) {
    const float4 c1 = *(const float4*)(cs + b * DIMC + k0 + akc * 4);
    const float4 c2 = *(const float4*)(ct + b * DIMC + k0 + akc * 4);
#pragma unroll
    for (int half = 0; half < 2; ++half) {
      int r = ar + 64 * half;
      float mu = half ? mu1 : mu0, rs = half ? rs1 : rs0;
      const float4 a = *(const float4*)(x + (size_t)(m0 + r) * DIMC + k0 + akc * 4);
      As[akc * 4 + 0][r] = fmaf((a.x - mu) * rs, c1.x, c2.x);
      As[akc * 4 + 1][r] = fmaf((a.y - mu) * rs, c1.y, c2.y);
      As[akc * 4 + 2][r] = fmaf((a.z - mu) * rs, c1.z, c2.z);
      As[akc * 4 + 3][r] = fmaf((a.w - mu) * rs, c1.w, c2.w);
    }
#pragma unroll
    for (int half = 0; half < 2; ++half) {
      int kr = bkr + 8 * half;
      *(float4*)&Bs[kr][bc4 * 4] =
          *(const float4*)(w_qkv + (size_t)(k0 + kr) * 1536 + n0 + bc4 * 4);
    }
    __syncthreads();
#pragma unroll
    for (int kk = 0; kk < 16; ++kk) {
      float a0[4], a1[4], b0[4], b1[4];
      *(float4*)a0 = *(const float4*)&As[kk][ty * 4];
      *(float4*)a1 = *(const float4*)&As[kk][64 + ty * 4];
      *(float4*)b0 = *(const float4*)&Bs[kk][tx * 4];
      *(float4*)b1 = *(const float4*)&Bs[kk][64 + tx * 4];
#pragma unroll
      for (int i = 0; i < 4; ++i)
#pragma unroll
        for (int j = 0; j < 4; ++j) {
          acc[i][j]         = fmaf(a0[i], b0[j], acc[i][j]);
          acc[i][j + 4]     = fmaf(a0[i], b1[j], acc[i][j + 4]);
          acc[i + 4][j]     = fmaf(a1[i], b0[j], acc[i + 4][j]);
          acc[i + 4][j + 4] = fmaf(a1[i], b1[j], acc[i + 4][j + 4]);
        }
    }
    __syncthreads();
  }

  // epilogue: section 0=q (rms+softmax+scale, row-major HID layout),
  //           1=k (rms, head layout), 2=v (raw, head layout -> d_out)
  int section = n0 >> 9;
  int h0 = (n0 & 511) >> 6;
  int cih = tx * 4;
#pragma unroll
  for (int i = 0; i < 8; ++i) {
    int r = (i < 4) ? (ty * 4 + i) : (64 + ty * 4 + i - 4);
    int gr = m0 + r;
    int nrow = gr & (NN - 1);
#pragma unroll
    for (int half = 0; half < 2; ++half) {
      int h = h0 + half;
      float v0 = acc[i][half * 4 + 0], v1 = acc[i][half * 4 + 1];
      float v2 = acc[i][half * 4 + 2], v3 = acc[i][half * 4 + 3];
      if (section == 2) {
        size_t o = ((size_t)(b * HH + h) * NN + nrow) * DHD + cih;
        *(float4*)(v_h + o) = make_float4(v0, v1, v2, v3);
      } else {
        float ss = v0 * v0 + v1 * v1 + v2 * v2 + v3 * v3;
#pragma unroll
        for (int m = 1; m < 16; m <<= 1) ss += __shfl_xor(ss, m);
        float sc = 8.f / fmaxf(sqrtf(ss), 1e-12f);   // sqrt(DH)=8
        const float* g = (section == 0) ? g_q : g_k;
        v0 *= sc * g[h * DHD + cih + 0];
        v1 *= sc * g[h * DHD + cih + 1];
        v2 *= sc * g[h * DHD + cih + 2];
        v3 *= sc * g[h * DHD + cih + 3];
        if (section == 0) {
          float mx = fmaxf(fmaxf(v0, v1), fmaxf(v2, v3));
#pragma unroll
          for (int m = 1; m < 16; m <<= 1) mx = fmaxf(mx, __shfl_xor(mx, m));
          v0 = __expf(v0 - mx); v1 = __expf(v1 - mx);
          v2 = __expf(v2 - mx); v3 = __expf(v3 - mx);
          float se = v0 + v1 + v2 + v3;
#pragma unroll
          for (int m = 1; m < 16; m <<= 1) se += __shfl_xor(se, m);
          float inv = 0.125f / se;                   // *DH^-0.5
          size_t o = (size_t)gr * HIDC + h * DHD + cih;
          *(float4*)(qs + o) = make_float4(v0 * inv, v1 * inv, v2 * inv, v3 * inv);
        } else {
          size_t o = ((size_t)(b * HH + h) * NN + nrow) * DHD + cih;
          *(float4*)(k_n + o) = make_float4(v0, v1, v2, v3);
        }
      }
    }
  }
}

// ---------------- K4: chunked column max of k_n over n ----------------
__global__ __launch_bounds__(256) void k_kmax_part(
    const float* __restrict__ k_n, float* __restrict__ kmp) {
  int bh = blockIdx.x, chunk = blockIdx.y;
  int d = threadIdx.x & 63, ng = threadIdx.x >> 6;
  const float* base = k_n + ((size_t)bh * NN + chunk * 1024) * DHD;
  float m = -1e30f;
  for (int n = ng; n < 1024; n += 4) m = fmaxf(m, base[(size_t)n * DHD + d]);
  __shared__ float red[256];
  red[threadIdx.x] = m;
  __syncthreads();
  if (threadIdx.x < 64) {
    m = fmaxf(fmaxf(red[d], red[64 + d]), fmaxf(red[128 + d], red[192 + d]));
    kmp[(bh * 8 + chunk) * DHD + d] = m;
  }
}

__global__ __launch_bounds__(256) void k_kmax_red(
    const float* __restrict__ kmp, float* __restrict__ km) {
  int i = blockIdx.x * 256 + threadIdx.x;  // 4096 total
  int bh = i >> 6, d = i & 63;
  float m = -1e30f;
  for (int c = 0; c < 8; ++c) m = fmaxf(m, kmp[(bh * 8 + c) * DHD + d]);
  km[i] = m;
}

// ---------------- K5: chunked context partials C~ = exp(k-max)^T V, Z ----------------
__global__ __launch_bounds__(256) void k_ctx_part(
    const float* __restrict__ k_n, const float* __restrict__ v_h,
    const float* __restrict__ km, float* __restrict__ Cp, float* __restrict__ Zp) {
  int bh = blockIdx.x, chunk = blockIdx.y;
  int d = threadIdx.x & 63, eg = threadIdx.x >> 6;
  size_t base = ((size_t)bh * NN + chunk * 1024) * DHD;
  float kmd = km[bh * DHD + d];
  float acc[16];
#pragma unroll
  for (int j = 0; j < 16; ++j) acc[j] = 0.f;
  float z = 0.f;
  for (int n = 0; n < 1024; ++n) {
    float ek = __expf(k_n[base + (size_t)n * DHD + d] - kmd);
    z += ek;
    const float4* vr = (const float4*)(v_h + base + (size_t)n * DHD + eg * 16);
    float4 q0 = vr[0], q1 = vr[1], q2 = vr[2], q3 = vr[3];
    acc[0] = fmaf(ek, q0.x, acc[0]);  acc[1] = fmaf(ek, q0.y, acc[1]);
    acc[2] = fmaf(ek, q0.z, acc[2]);  acc[3] = fmaf(ek, q0.w, acc[3]);
    acc[4] = fmaf(ek, q1.x, acc[4]);  acc[5] = fmaf(ek, q1.y, acc[5]);
    acc[6] = fmaf(ek, q1.z, acc[6]);  acc[7] = fmaf(ek, q1.w, acc[7]);
    acc[8] = fmaf(ek, q2.x, acc[8]);  acc[9] = fmaf(ek, q2.y, acc[9]);
    acc[10] = fmaf(ek, q2.z, acc[10]); acc[11] = fmaf(ek, q2.w, acc[11]);
    acc[12] = fmaf(ek, q3.x, acc[12]); acc[13] = fmaf(ek, q3.y, acc[13]);
    acc[14] = fmaf(ek, q3.z, acc[14]); acc[15] = fmaf(ek, q3.w, acc[15]);
  }
  size_t co = ((size_t)(bh * 8 + chunk) * DHD + d) * DHD + eg * 16;
  float4* cp4 = (float4*)(Cp + co);
  cp4[0] = make_float4(acc[0], acc[1], acc[2], acc[3]);
  cp4[1] = make_float4(acc[4], acc[5], acc[6], acc[7]);
  cp4[2] = make_float4(acc[8], acc[9], acc[10], acc[11]);
  cp4[3] = make_float4(acc[12], acc[13], acc[14], acc[15]);
  if (eg == 0) Zp[(bh * 8 + chunk) * DHD + d] = z;
}

// ---------------- K6a: reduce partials, normalize by Z ----------------
__global__ __launch_bounds__(256) void k_ctx_red(
    const float* __restrict__ Cp, const float* __restrict__ Zp, float* __restrict__ Cn) {
  int bh = blockIdx.x;
  int tid = threadIdx.x;
  __shared__ float zs[64];
  if (tid < 64) {
    float zt = 0.f;
    for (int c = 0; c < 8; ++c) zt += Zp[(bh * 8 + c) * DHD + tid];
    zs[tid] = 1.f / zt;
  }
  __syncthreads();
  for (int i = tid; i < DHD * DHD; i += 256) {
    int d = i >> 6;
    float s = 0.f;
    for (int c = 0; c < 8; ++c) s += Cp[(size_t)(bh * 8 + c) * (DHD * DHD) + i];
    Cn[(size_t)bh * (DHD * DHD) + i] = s * zs[d];
  }
}

// ---------------- K6b: Mstack[b][64h+d][j] = sum_e C[b,h,d,e] * w_out[64h+e][j] ----------------
// grid (64, 2): block handles j-half of 256 columns.
__global__ __launch_bounds__(256) void k_mstack(
    const float* __restrict__ Cn, const float* __restrict__ w_out, float* __restrict__ Ms) {
  int bh = blockIdx.x;
  int b = bh >> 3, h = bh & 7;
  int j0 = blockIdx.y * 256;
  int tid = threadIdx.x;
  __shared__ float Cs[64][64];
  for (int i = tid; i < 4096; i += 256) Cs[i >> 6][i & 63] = Cn[(size_t)bh * 4096 + i];
  __syncthreads();
  for (int i = tid; i < DHD * 256; i += 256) {
    int d = i >> 8, j = j0 + (i & 255);
    float s = 0.f;
#pragma unroll 8
    for (int e = 0; e < 64; ++e) s = fmaf(Cs[d][e], w_out[(size_t)(h * 64 + e) * DIMC + j], s);
    Ms[((size_t)b * DIMC + h * 64 + d) * DIMC + j] = s;
  }
}

// ---------------- K7: out = qs @ Mstack[b]  (tile 128x128, BK=16) ----------------
__global__ __launch_bounds__(256) void k_out_gemm(
    const float* __restrict__ qs, const float* __restrict__ Ms, float* __restrict__ out) {
  __shared__ float As[16][128];
  __shared__ float Bs[16][128];
  int tid = threadIdx.x;
  int tx = tid & 15, ty = tid >> 4;
  int n0 = blockIdx.x * 128;
  int m0 = blockIdx.y * 128;
  int b = m0 >> 13;
  const float* Bm = Ms + (size_t)b * DIMC * DIMC;

  float acc[8][8];
#pragma unroll
  for (int i = 0; i < 8; ++i)
#pragma unroll
    for (int j = 0; j < 8; ++j) acc[i][j] = 0.f;

  int ar = tid >> 2, akc = tid & 3;
  int bkr = tid >> 5, bc4 = tid & 31;

  for (int k0 = 0; k0 < HIDC; k0 += 16) {
#pragma unroll
    for (int half = 0; half < 2; ++half) {
      int r = ar + 64 * half;
      const float4 a = *(const float4*)(qs + (size_t)(m0 + r) * HIDC + k0 + akc * 4);
      As[akc * 4 + 0][r] = a.x;
      As[akc * 4 + 1][r] = a.y;
      As[akc * 4 + 2][r] = a.z;
      As[akc * 4 + 3][r] = a.w;
    }
#pragma unroll
    for (int half = 0; half < 2; ++half) {
      int kr = bkr + 8 * half;
      *(float4*)&Bs[kr][bc4 * 4] =
          *(const float4*)(Bm + (size_t)(k0 + kr) * DIMC + n0 + bc4 * 4);
    }
    __syncthreads();
#pragma unroll
    for (int kk = 0; kk < 16; ++kk) {
      float a0[4], a1[4], b0[4], b1[4];
      *(float4*)a0 = *(const float4*)&As[kk][ty * 4];
      *(float4*)a1 = *(const float4*)&As[kk][64 + ty * 4];
      *(float4*)b0 = *(const float4*)&Bs[kk][tx * 4];
      *(float4*)b1 = *(const float4*)&Bs[kk][64 + tx * 4];
#pragma unroll
      for (int i = 0; i < 4; ++i)
#pragma unroll
        for (int j = 0; j < 4; ++j) {
          acc[i][j]         = fmaf(a0[i], b0[j], acc[i][j]);
          acc[i][j + 4]     = fmaf(a0[i], b1[j], acc[i][j + 4]);
          acc[i + 4][j]     = fmaf(a1[i], b0[j], acc[i + 4][j]);
          acc[i + 4][j + 4] = fmaf(a1[i], b1[j], acc[i + 4][j + 4]);
        }
    }
    __syncthreads();
  }
#pragma unroll
  for (int i = 0; i < 8; ++i) {
    int r = (i < 4) ? (ty * 4 + i) : (64 + ty * 4 + i - 4);
    size_t ro = (size_t)(m0 + r) * DIMC + n0;
    *(float4*)(out + ro + tx * 4)      = make_float4(acc[i][0], acc[i][1], acc[i][2], acc[i][3]);
    *(float4*)(out + ro + 64 + tx * 4) = make_float4(acc[i][4], acc[i][5], acc[i][6], acc[i][7]);
  }
}

// ---------------- K8: in-place final LayerNorm on d_out ----------------
__global__ __launch_bounds__(256) void k_ln_out(
    float* __restrict__ y, const float* __restrict__ gamma) {
  int row = blockIdx.x * 4 + (threadIdx.x >> 6);
  int lane = threadIdx.x & 63;
  float4* yr = (float4*)(y + (size_t)row * DIMC);
  float4 v0 = yr[lane], v1 = yr[lane + 64];
  float s = v0.x + v0.y + v0.z + v0.w + v1.x + v1.y + v1.z + v1.w;
  float s2 = v0.x * v0.x + v0.y * v0.y + v0.z * v0.z + v0.w * v0.w +
             v1.x * v1.x + v1.y * v1.y + v1.z * v1.z + v1.w * v1.w;
#pragma unroll
  for (int m = 1; m < 64; m <<= 1) { s += __shfl_xor(s, m); s2 += __shfl_xor(s2, m); }
  float mu = s * (1.f / DIMC);
  float rs = rsqrtf(s2 * (1.f / DIMC) - mu * mu + 1e-5f);
  const float4* g = (const float4*)gamma;
  float4 g0 = g[lane], g1 = g[lane + 64];
  v0.x = (v0.x - mu) * rs * g0.x; v0.y = (v0.y - mu) * rs * g0.y;
  v0.z = (v0.z - mu) * rs * g0.z; v0.w = (v0.w - mu) * rs * g0.w;
  v1.x = (v1.x - mu) * rs * g1.x; v1.y = (v1.y - mu) * rs * g1.y;
  v1.z = (v1.z - mu) * rs * g1.z; v1.w = (v1.w - mu) * rs * g1.w;
  yr[lane] = v0; yr[lane + 64] = v1;
}

extern "C" void kernel_launch(void* const* d_in, const int* in_sizes, int n_in,
                              void* d_out, int out_size, void* d_ws, size_t ws_size,
                              hipStream_t stream) {
  (void)in_sizes; (void)n_in; (void)out_size; (void)ws_size;
  const float* x        = (const float*)d_in[0];
  const float* timev    = (const float*)d_in[1];
  const float* ln_gamma = (const float*)d_in[2];
  const float* w_time   = (const float*)d_in[3];
  const float* b_time   = (const float*)d_in[4];
  const float* w_qkv    = (const float*)d_in[5];
  const float* g_q      = (const float*)d_in[6];
  const float* g_k      = (const float*)d_in[7];
  const float* w_out    = (const float*)d_in[8];
  const float* ln_out_g = (const float*)d_in[9];
  float* out = (float*)d_out;

  // workspace layout (floats); total ~287 MB
  float* w    = (float*)d_ws;
  float* cs   = w;                 // 4096
  float* ct   = cs + 4096;         // 4096
  float* mean = ct + 4096;         // 65536
  float* rstd = mean + 65536;      // 65536
  float* kmp  = rstd + 65536;      // 32768
  float* km   = kmp + 32768;       // 4096
  float* Zp   = km + 4096;         // 32768
  float* Cp   = Zp + 32768;        // 2097152
  float* Cn   = Cp + 2097152;      // 262144
  float* Ms   = Cn + 262144;       // 2097152
  float* qs   = Ms + 2097152;      // 33554432
  float* k_n  = qs + 33554432;     // 33554432
  float* v_h  = out;               // V lives in d_out until K7 overwrites it

  hipLaunchKernelGGL(k_time_mlp, dim3(BB, 2), dim3(256), 0, stream,
                     timev, w_time, b_time, ln_gamma, cs, ct);
  hipLaunchKernelGGL(k_rowstats, dim3(BB * NN / 4), dim3(256), 0, stream, x, mean, rstd);
  hipLaunchKernelGGL(k_qkv_gemm, dim3(12, 512), dim3(256), 0, stream,
                     x, w_qkv, mean, rstd, cs, ct, g_q, g_k, qs, k_n, v_h);
  hipLaunchKernelGGL(k_kmax_part, dim3(64, 8), dim3(256), 0, stream, k_n, kmp);
  hipLaunchKernelGGL(k_kmax_red, dim3(16), dim3(256), 0, stream, kmp, km);
  hipLaunchKernelGGL(k_ctx_part, dim3(64, 8), dim3(256), 0, stream, k_n, v_h, km, Cp, Zp);
  hipLaunchKernelGGL(k_ctx_red, dim3(64), dim3(256), 0, stream, Cp, Zp, Cn);
  hipLaunchKernelGGL(k_mstack, dim3(64, 2), dim3(256), 0, stream, Cn, w_out, Ms);
  hipLaunchKernelGGL(k_out_gemm, dim3(4, 512), dim3(256), 0, stream, qs, Ms, out);
  hipLaunchKernelGGL(k_ln_out, dim3(BB * NN / 4), dim3(256), 0, stream, out, ln_out_g);
}

// Round 3
// 1396.169 us; speedup vs baseline: 1.7724x; 1.7724x over previous
//
#include <hip/hip_runtime.h>
#include <cstdint>
#include <cmath>

#define BB   8
#define NN   8192
#define DIMC 512
#define HH   8
#define DHD  64
#define HIDC 512
#define TCDC 512

typedef __attribute__((ext_vector_type(8))) short bf16x8;
typedef __attribute__((ext_vector_type(4))) float f32x4;

// exact truncation split: v = hi + rem, |rem| <= 2^-8|v|; lo = trunc-bf16(rem)
__device__ inline void split2(float v, short* hi, short* lo) {
  unsigned u = __float_as_uint(v);
  float hf = __uint_as_float(u & 0xFFFF0000u);
  *hi = (short)(u >> 16);
  *lo = (short)(__float_as_uint(v - hf) >> 16);
}

__device__ inline void gload16(const void* g, void* l) {
  __builtin_amdgcn_global_load_lds(
      (const __attribute__((address_space(1))) unsigned*)g,
      (__attribute__((address_space(3))) unsigned*)l, 16, 0, 0);
}

// ---------------- K0: w_qkv -> bf16 hi/lo tiled image [nblk12][ktile16][kblk4][col128][kk8]
__global__ __launch_bounds__(256) void k_prep_w(
    const float* __restrict__ w, short* __restrict__ whi, short* __restrict__ wlo) {
  int nblk = blockIdx.x, ktile = blockIdx.y;
  int tid = threadIdx.x;
  size_t obase = ((size_t)(nblk * 16 + ktile)) * 4096;
  for (int i = tid; i < 4096; i += 256) {
    int kl = i >> 7, col = i & 127;
    float v = w[(size_t)(ktile * 32 + kl) * 1536 + nblk * 128 + col];
    short h, l; split2(v, &h, &l);
    size_t o = obase + ((size_t)((kl >> 3) * 128 + col)) * 8 + (kl & 7);
    whi[o] = h; wlo[o] = l;
  }
}

// ---------------- K1: t = silu(time) @ w_time + b_time -> cs, ct ----------------
__global__ __launch_bounds__(256) void k_time_mlp(
    const float* __restrict__ timev, const float* __restrict__ w_time,
    const float* __restrict__ b_time, const float* __restrict__ ln_gamma,
    float* __restrict__ cs, float* __restrict__ ct) {
  int b = blockIdx.x;
  int d = blockIdx.y * 256 + threadIdx.x;
  int tid = threadIdx.x;
  __shared__ float st[TCDC];
  for (int k = tid; k < TCDC; k += 256) {
    float v = timev[b * TCDC + k];
    st[k] = v / (1.f + __expf(-v));
  }
  __syncthreads();
  float accs = b_time[d];
  float acct = b_time[DIMC + d];
  for (int k = 0; k < TCDC; ++k) {
    float s = st[k];
    accs = fmaf(s, w_time[k * (2 * DIMC) + d], accs);
    acct = fmaf(s, w_time[k * (2 * DIMC) + DIMC + d], acct);
  }
  cs[b * DIMC + d] = ln_gamma[d] * (1.f + accs);
  ct[b * DIMC + d] = acct;
}

// ---------------- K2: per-row mean / rstd of x ----------------
__global__ __launch_bounds__(256) void k_rowstats(
    const float* __restrict__ x, float* __restrict__ mean, float* __restrict__ rstd) {
  int row = blockIdx.x * 4 + (threadIdx.x >> 6);
  int lane = threadIdx.x & 63;
  const float4* xr = (const float4*)(x + (size_t)row * DIMC);
  float s = 0.f, s2 = 0.f;
#pragma unroll
  for (int i = 0; i < 2; ++i) {
    float4 v = xr[lane + 64 * i];
    s  += v.x + v.y + v.z + v.w;
    s2 += v.x * v.x + v.y * v.y + v.z * v.z + v.w * v.w;
  }
#pragma unroll
  for (int m = 1; m < 64; m <<= 1) { s += __shfl_xor(s, m); s2 += __shfl_xor(s2, m); }
  float mu = s * (1.f / DIMC);
  float var = s2 * (1.f / DIMC) - mu * mu;
  if (lane == 0) { mean[row] = mu; rstd[row] = rsqrtf(var + 1e-5f); }
}

// ---------------- K3: split-bf16 MFMA GEMM (LN+mod fused) with q/k/v epilogue ----
// tile 128x128, BK=32, 4 waves (2x2), each wave 4x4 frags of 16x16x32
__global__ __launch_bounds__(256) void k_qkv_gemm(
    const float* __restrict__ x,
    const short* __restrict__ whi, const short* __restrict__ wlo,
    const float* __restrict__ mean, const float* __restrict__ rstd,
    const float* __restrict__ cs, const float* __restrict__ ct,
    const float* __restrict__ g_q, const float* __restrict__ g_k,
    short* __restrict__ qhi, short* __restrict__ qlo,
    float* __restrict__ k_n, float* __restrict__ v_h) {
  __shared__ __align__(16) short As[2][4][128][8];   // [hi/lo][kblk][row^kblk][kk]
  __shared__ __align__(16) short Bs[2][4][128][8];   // [hi/lo][kblk][col][kk] linear
  int tid = threadIdx.x;
  int lane = tid & 63, wave = tid >> 6;
  int wr = wave >> 1, wc = wave & 1;
  int l15 = lane & 15, g = lane >> 4;
  int nblk = blockIdx.x, n0 = nblk * 128;
  int m0 = blockIdx.y * 128;
  int b = m0 >> 13;

  f32x4 acc[4][4];
#pragma unroll
  for (int mi = 0; mi < 4; ++mi)
#pragma unroll
    for (int ni = 0; ni < 4; ++ni) acc[mi][ni] = (f32x4){0.f, 0.f, 0.f, 0.f};

  int arow = tid >> 2;   // 0..63 (plus +64 in second half)
  int akc  = tid & 3;    // k-chunk of 8
  float mu0 = mean[m0 + arow],      rs0 = rstd[m0 + arow];
  float mu1 = mean[m0 + arow + 64], rs1 = rstd[m0 + arow + 64];

  for (int kt = 0; kt < 16; ++kt) {
    // ---- A staging: fp32 -> LN-mod -> split -> LDS (XOR swizzle row^kc) ----
    const float4 c1a = *(const float4*)(cs + b * DIMC + kt * 32 + akc * 8);
    const float4 c1b = *(const float4*)(cs + b * DIMC + kt * 32 + akc * 8 + 4);
    const float4 c2a = *(const float4*)(ct + b * DIMC + kt * 32 + akc * 8);
    const float4 c2b = *(const float4*)(ct + b * DIMC + kt * 32 + akc * 8 + 4);
#pragma unroll
    for (int half = 0; half < 2; ++half) {
      int row = arow + half * 64;
      float mu = half ? mu1 : mu0, rs = half ? rs1 : rs0;
      const float4* xa = (const float4*)(x + (size_t)(m0 + row) * DIMC + kt * 32 + akc * 8);
      float4 a0 = xa[0], a1 = xa[1];
      float vv[8];
      vv[0] = fmaf((a0.x - mu) * rs, c1a.x, c2a.x);
      vv[1] = fmaf((a0.y - mu) * rs, c1a.y, c2a.y);
      vv[2] = fmaf((a0.z - mu) * rs, c1a.z, c2a.z);
      vv[3] = fmaf((a0.w - mu) * rs, c1a.w, c2a.w);
      vv[4] = fmaf((a1.x - mu) * rs, c1b.x, c2b.x);
      vv[5] = fmaf((a1.y - mu) * rs, c1b.y, c2b.y);
      vv[6] = fmaf((a1.z - mu) * rs, c1b.z, c2b.z);
      vv[7] = fmaf((a1.w - mu) * rs, c1b.w, c2b.w);
      bf16x8 vh, vl;
#pragma unroll
      for (int i = 0; i < 8; ++i) {
        short hh, ll; split2(vv[i], &hh, &ll);
        vh[i] = hh; vl[i] = ll;
      }
      *(bf16x8*)&As[0][akc][row ^ akc][0] = vh;
      *(bf16x8*)&As[1][akc][row ^ akc][0] = vl;
    }
    // ---- B staging: contiguous image copy via global_load_lds ----
    size_t boff = ((size_t)(nblk * 16 + kt)) * 4096;
#pragma unroll
    for (int h = 0; h < 2; ++h) {
      const short* src = (h ? wlo : whi) + boff;
      short* dst = &Bs[h][0][0][0];
#pragma unroll
      for (int r = 0; r < 2; ++r) {
        int ci = (r * 4 + wave) * 64 + lane;
        gload16(src + (size_t)ci * 8, dst + (r * 4 + wave) * 512);
      }
    }
    __syncthreads();
    // ---- fragments + 48 MFMA ----
    bf16x8 ah[4], al[4], bh[4], bl[4];
#pragma unroll
    for (int i = 0; i < 4; ++i) {
      int row = wr * 64 + i * 16 + l15;
      ah[i] = *(const bf16x8*)&As[0][g][row ^ g][0];
      al[i] = *(const bf16x8*)&As[1][g][row ^ g][0];
      int col = wc * 64 + i * 16 + l15;
      bh[i] = *(const bf16x8*)&Bs[0][g][col][0];
      bl[i] = *(const bf16x8*)&Bs[1][g][col][0];
    }
#pragma unroll
    for (int mi = 0; mi < 4; ++mi)
#pragma unroll
      for (int ni = 0; ni < 4; ++ni) {
        acc[mi][ni] = __builtin_amdgcn_mfma_f32_16x16x32_bf16(ah[mi], bh[ni], acc[mi][ni], 0, 0, 0);
        acc[mi][ni] = __builtin_amdgcn_mfma_f32_16x16x32_bf16(ah[mi], bl[ni], acc[mi][ni], 0, 0, 0);
        acc[mi][ni] = __builtin_amdgcn_mfma_f32_16x16x32_bf16(al[mi], bh[ni], acc[mi][ni], 0, 0, 0);
      }
    __syncthreads();
  }

  // ---- epilogue: section 0=q (rms+softmax -> qs image bf16), 1=k (rms -> k_n), 2=v ----
  int section = n0 >> 9;
  int h = ((n0 & 511) >> 6) + wc;   // head, uniform per wave
  float gq[4], gk[4];
  int kt_[4], kb_[4], kk_[4];
#pragma unroll
  for (int ni = 0; ni < 4; ++ni) {
    int ch = ni * 16 + l15;          // col in head 0..63
    int hid = h * 64 + ch;
    gq[ni] = g_q[hid]; gk[ni] = g_k[hid];
    kt_[ni] = hid >> 5; kb_[ni] = (hid >> 3) & 3; kk_[ni] = hid & 7;
  }
#pragma unroll
  for (int mi = 0; mi < 4; ++mi) {
#pragma unroll
    for (int rg = 0; rg < 4; ++rg) {
      int grow = m0 + wr * 64 + mi * 16 + g * 4 + rg;
      float v[4];
#pragma unroll
      for (int ni = 0; ni < 4; ++ni) v[ni] = acc[mi][ni][rg];
      if (section == 2) {
        int nrow = grow & (NN - 1);
#pragma unroll
        for (int ni = 0; ni < 4; ++ni)
          v_h[((size_t)(b * HH + h) * NN + nrow) * DHD + ni * 16 + l15] = v[ni];
      } else {
        float ss = v[0] * v[0] + v[1] * v[1] + v[2] * v[2] + v[3] * v[3];
#pragma unroll
        for (int mk = 1; mk < 16; mk <<= 1) ss += __shfl_xor(ss, mk);
        float sc = 8.f / fmaxf(sqrtf(ss), 1e-12f);
        if (section == 0) {
#pragma unroll
          for (int ni = 0; ni < 4; ++ni) v[ni] *= sc * gq[ni];
          float mx = fmaxf(fmaxf(v[0], v[1]), fmaxf(v[2], v[3]));
#pragma unroll
          for (int mk = 1; mk < 16; mk <<= 1) mx = fmaxf(mx, __shfl_xor(mx, mk));
#pragma unroll
          for (int ni = 0; ni < 4; ++ni) v[ni] = __expf(v[ni] - mx);
          float se = v[0] + v[1] + v[2] + v[3];
#pragma unroll
          for (int mk = 1; mk < 16; mk <<= 1) se += __shfl_xor(se, mk);
          float inv = 0.125f / se;
          int mblk = grow >> 7, r = grow & 127;
#pragma unroll
          for (int ni = 0; ni < 4; ++ni) {
            short hh, ll; split2(v[ni] * inv, &hh, &ll);
            size_t o = (((size_t)(mblk * 16 + kt_[ni]) * 4 + kb_[ni]) * 128 + r) * 8 + kk_[ni];
            qhi[o] = hh; qlo[o] = ll;
          }
        } else {
          int nrow = grow & (NN - 1);
#pragma unroll
          for (int ni = 0; ni < 4; ++ni)
            k_n[((size_t)(b * HH + h) * NN + nrow) * DHD + ni * 16 + l15] = v[ni] * sc * gk[ni];
        }
      }
    }
  }
}

// ---------------- K4: chunked column max of k_n over n ----------------
__global__ __launch_bounds__(256) void k_kmax_part(
    const float* __restrict__ k_n, float* __restrict__ kmp) {
  int bh = blockIdx.x, chunk = blockIdx.y;
  int d = threadIdx.x & 63, ng = threadIdx.x >> 6;
  const float* base = k_n + ((size_t)bh * NN + chunk * 1024) * DHD;
  float m = -1e30f;
  for (int n = ng; n < 1024; n += 4) m = fmaxf(m, base[(size_t)n * DHD + d]);
  __shared__ float red[256];
  red[threadIdx.x] = m;
  __syncthreads();
  if (threadIdx.x < 64) {
    m = fmaxf(fmaxf(red[d], red[64 + d]), fmaxf(red[128 + d], red[192 + d]));
    kmp[(bh * 8 + chunk) * DHD + d] = m;
  }
}

__global__ __launch_bounds__(256) void k_kmax_red(
    const float* __restrict__ kmp, float* __restrict__ km) {
  int i = blockIdx.x * 256 + threadIdx.x;
  int bh = i >> 6, d = i & 63;
  float m = -1e30f;
  for (int c = 0; c < 8; ++c) m = fmaxf(m, kmp[(bh * 8 + c) * DHD + d]);
  km[i] = m;
}

// ---------------- K5: chunked context partials C~ = exp(k-max)^T V, Z ----------------
__global__ __launch_bounds__(256) void k_ctx_part(
    const float* __restrict__ k_n, const float* __restrict__ v_h,
    const float* __restrict__ km, float* __restrict__ Cp, float* __restrict__ Zp) {
  int bh = blockIdx.x, chunk = blockIdx.y;
  int d = threadIdx.x & 63, eg = threadIdx.x >> 6;
  size_t base = ((size_t)bh * NN + chunk * 1024) * DHD;
  float kmd = km[bh * DHD + d];
  float acc[16];
#pragma unroll
  for (int j = 0; j < 16; ++j) acc[j] = 0.f;
  float z = 0.f;
  for (int n = 0; n < 1024; ++n) {
    float ek = __expf(k_n[base + (size_t)n * DHD + d] - kmd);
    z += ek;
    const float4* vr = (const float4*)(v_h + base + (size_t)n * DHD + eg * 16);
    float4 q0 = vr[0], q1 = vr[1], q2 = vr[2], q3 = vr[3];
    acc[0] = fmaf(ek, q0.x, acc[0]);   acc[1] = fmaf(ek, q0.y, acc[1]);
    acc[2] = fmaf(ek, q0.z, acc[2]);   acc[3] = fmaf(ek, q0.w, acc[3]);
    acc[4] = fmaf(ek, q1.x, acc[4]);   acc[5] = fmaf(ek, q1.y, acc[5]);
    acc[6] = fmaf(ek, q1.z, acc[6]);   acc[7] = fmaf(ek, q1.w, acc[7]);
    acc[8] = fmaf(ek, q2.x, acc[8]);   acc[9] = fmaf(ek, q2.y, acc[9]);
    acc[10] = fmaf(ek, q2.z, acc[10]); acc[11] = fmaf(ek, q2.w, acc[11]);
    acc[12] = fmaf(ek, q3.x, acc[12]); acc[13] = fmaf(ek, q3.y, acc[13]);
    acc[14] = fmaf(ek, q3.z, acc[14]); acc[15] = fmaf(ek, q3.w, acc[15]);
  }
  size_t co = ((size_t)(bh * 8 + chunk) * DHD + d) * DHD + eg * 16;
  float4* cp4 = (float4*)(Cp + co);
  cp4[0] = make_float4(acc[0], acc[1], acc[2], acc[3]);
  cp4[1] = make_float4(acc[4], acc[5], acc[6], acc[7]);
  cp4[2] = make_float4(acc[8], acc[9], acc[10], acc[11]);
  cp4[3] = make_float4(acc[12], acc[13], acc[14], acc[15]);
  if (eg == 0) Zp[(bh * 8 + chunk) * DHD + d] = z;
}

// ---------------- K6a: reduce partials, normalize by Z ----------------
__global__ __launch_bounds__(256) void k_ctx_red(
    const float* __restrict__ Cp, const float* __restrict__ Zp, float* __restrict__ Cn) {
  int bh = blockIdx.x;
  int tid = threadIdx.x;
  __shared__ float zs[64];
  if (tid < 64) {
    float zt = 0.f;
    for (int c = 0; c < 8; ++c) zt += Zp[(bh * 8 + c) * DHD + tid];
    zs[tid] = 1.f / zt;
  }
  __syncthreads();
  for (int i = tid; i < DHD * DHD; i += 256) {
    int d = i >> 6;
    float s = 0.f;
    for (int c = 0; c < 8; ++c) s += Cp[(size_t)(bh * 8 + c) * (DHD * DHD) + i];
    Cn[(size_t)bh * (DHD * DHD) + i] = s * zs[d];
  }
}

// ---------------- K6b: Ms image = C @ w_out (bf16 hi/lo, tiled for K7) ----------------
__global__ __launch_bounds__(256) void k_mstack(
    const float* __restrict__ Cn, const float* __restrict__ w_out,
    short* __restrict__ mhi, short* __restrict__ mlo) {
  int bh = blockIdx.x;
  int b = bh >> 3, h = bh & 7;
  int j0 = blockIdx.y * 256;
  int tid = threadIdx.x;
  int d = tid & 63, jg = tid >> 6;
  __shared__ float Cs[64][65];   // +1 pad: unpadded was a 64-way bank conflict
  for (int i = tid; i < 4096; i += 256) Cs[i >> 6][i & 63] = Cn[(size_t)bh * 4096 + i];
  __syncthreads();
  int ktile = h * 2 + (d >> 5), kblk = (d >> 3) & 3, kk = d & 7;
  for (int jj = 0; jj < 64; ++jj) {
    int j = j0 + jg * 64 + jj;
    float s = 0.f;
#pragma unroll 16
    for (int e = 0; e < 64; ++e) s = fmaf(Cs[d][e], w_out[(size_t)(h * 64 + e) * DIMC + j], s);
    short hh, ll; split2(s, &hh, &ll);
    size_t o = ((((size_t)(b * 4 + (j >> 7)) * 16 + ktile) * 4 + kblk) * 128 + (j & 127)) * 8 + kk;
    mhi[o] = hh; mlo[o] = ll;
  }
}

// ---------------- K7: out = qs @ Ms[b] — both operands via global_load_lds ----------------
__global__ __launch_bounds__(256) void k_out_gemm(
    const short* __restrict__ qhi, const short* __restrict__ qlo,
    const short* __restrict__ mhi, const short* __restrict__ mlo,
    float* __restrict__ out) {
  __shared__ __align__(16) short As[2][4][128][8];   // linear (gload_lds dest)
  __shared__ __align__(16) short Bs[2][4][128][8];
  int tid = threadIdx.x;
  int lane = tid & 63, wave = tid >> 6;
  int wr = wave >> 1, wc = wave & 1;
  int l15 = lane & 15, g = lane >> 4;
  int nblk = blockIdx.x, n0 = nblk * 128;
  int mblk = blockIdx.y, m0 = mblk * 128;
  int b = m0 >> 13;

  f32x4 acc[4][4];
#pragma unroll
  for (int mi = 0; mi < 4; ++mi)
#pragma unroll
    for (int ni = 0; ni < 4; ++ni) acc[mi][ni] = (f32x4){0.f, 0.f, 0.f, 0.f};

  for (int kt = 0; kt < 16; ++kt) {
    size_t aoff = ((size_t)(mblk * 16 + kt)) * 4096;
    size_t boff = ((size_t)((b * 4 + nblk) * 16 + kt)) * 4096;
#pragma unroll
    for (int h = 0; h < 2; ++h) {
      const short* asrc = (h ? qlo : qhi) + aoff;
      const short* bsrc = (h ? mlo : mhi) + boff;
#pragma unroll
      for (int r = 0; r < 2; ++r) {
        int ci = (r * 4 + wave) * 64 + lane;
        gload16(asrc + (size_t)ci * 8, &As[h][0][0][0] + (r * 4 + wave) * 512);
        gload16(bsrc + (size_t)ci * 8, &Bs[h][0][0][0] + (r * 4 + wave) * 512);
      }
    }
    __syncthreads();
    bf16x8 ah[4], al[4], bh[4], bl[4];
#pragma unroll
    for (int i = 0; i < 4; ++i) {
      int row = wr * 64 + i * 16 + l15;
      ah[i] = *(const bf16x8*)&As[0][g][row][0];
      al[i] = *(const bf16x8*)&As[1][g][row][0];
      int col = wc * 64 + i * 16 + l15;
      bh[i] = *(const bf16x8*)&Bs[0][g][col][0];
      bl[i] = *(const bf16x8*)&Bs[1][g][col][0];
    }
#pragma unroll
    for (int mi = 0; mi < 4; ++mi)
#pragma unroll
      for (int ni = 0; ni < 4; ++ni) {
        acc[mi][ni] = __builtin_amdgcn_mfma_f32_16x16x32_bf16(ah[mi], bh[ni], acc[mi][ni], 0, 0, 0);
        acc[mi][ni] = __builtin_amdgcn_mfma_f32_16x16x32_bf16(ah[mi], bl[ni], acc[mi][ni], 0, 0, 0);
        acc[mi][ni] = __builtin_amdgcn_mfma_f32_16x16x32_bf16(al[mi], bh[ni], acc[mi][ni], 0, 0, 0);
      }
    __syncthreads();
  }
#pragma unroll
  for (int mi = 0; mi < 4; ++mi)
#pragma unroll
    for (int rg = 0; rg < 4; ++rg) {
      int grow = m0 + wr * 64 + mi * 16 + g * 4 + rg;
#pragma unroll
      for (int ni = 0; ni < 4; ++ni)
        out[(size_t)grow * DIMC + n0 + wc * 64 + ni * 16 + l15] = acc[mi][ni][rg];
    }
}

// ---------------- K8: in-place final LayerNorm on d_out ----------------
__global__ __launch_bounds__(256) void k_ln_out(
    float* __restrict__ y, const float* __restrict__ gamma) {
  int row = blockIdx.x * 4 + (threadIdx.x >> 6);
  int lane = threadIdx.x & 63;
  float4* yr = (float4*)(y + (size_t)row * DIMC);
  float4 v0 = yr[lane], v1 = yr[lane + 64];
  float s = v0.x + v0.y + v0.z + v0.w + v1.x + v1.y + v1.z + v1.w;
  float s2 = v0.x * v0.x + v0.y * v0.y + v0.z * v0.z + v0.w * v0.w +
             v1.x * v1.x + v1.y * v1.y + v1.z * v1.z + v1.w * v1.w;
#pragma unroll
  for (int m = 1; m < 64; m <<= 1) { s += __shfl_xor(s, m); s2 += __shfl_xor(s2, m); }
  float mu = s * (1.f / DIMC);
  float rs = rsqrtf(s2 * (1.f / DIMC) - mu * mu + 1e-5f);
  const float4* gp = (const float4*)gamma;
  float4 g0 = gp[lane], g1 = gp[lane + 64];
  v0.x = (v0.x - mu) * rs * g0.x; v0.y = (v0.y - mu) * rs * g0.y;
  v0.z = (v0.z - mu) * rs * g0.z; v0.w = (v0.w - mu) * rs * g0.w;
  v1.x = (v1.x - mu) * rs * g1.x; v1.y = (v1.y - mu) * rs * g1.y;
  v1.z = (v1.z - mu) * rs * g1.z; v1.w = (v1.w - mu) * rs * g1.w;
  yr[lane] = v0; yr[lane + 64] = v1;
}

extern "C" void kernel_launch(void* const* d_in, const int* in_sizes, int n_in,
                              void* d_out, int out_size, void* d_ws, size_t ws_size,
                              hipStream_t stream) {
  (void)in_sizes; (void)n_in; (void)out_size; (void)ws_size;
  const float* x        = (const float*)d_in[0];
  const float* timev    = (const float*)d_in[1];
  const float* ln_gamma = (const float*)d_in[2];
  const float* w_time   = (const float*)d_in[3];
  const float* b_time   = (const float*)d_in[4];
  const float* w_qkv    = (const float*)d_in[5];
  const float* g_q      = (const float*)d_in[6];
  const float* g_k      = (const float*)d_in[7];
  const float* w_out    = (const float*)d_in[8];
  const float* ln_out_g = (const float*)d_in[9];
  float* out = (float*)d_out;

  // workspace layout (~282 MB)
  float* cs   = (float*)d_ws;          // 4096
  float* ct   = cs + 4096;             // 4096
  float* mean = ct + 4096;             // 65536
  float* rstd = mean + 65536;          // 65536
  float* kmp  = rstd + 65536;          // 32768
  float* km   = kmp + 32768;           // 4096
  float* Zp   = km + 4096;             // 32768
  float* Cp   = Zp + 32768;            // 2097152 (8MB; dead after k_ctx_red)
  float* Cn   = Cp + 2097152;          // 262144
  float* k_n  = Cn + 262144;           // 33554432 (128MB)
  short* whi  = (short*)(k_n + 33554432);  // 786432
  short* wlo  = whi + 786432;
  short* qhi  = wlo + 786432;          // 33554432 (64MB)
  short* qlo  = qhi + 33554432;        // 64MB
  short* mhi  = (short*)Cp;            // alias dead Cp (8MB exact)
  short* mlo  = mhi + 2097152;
  float* v_h  = out;                   // V lives in d_out until K7 overwrites it

  hipLaunchKernelGGL(k_prep_w, dim3(12, 16), dim3(256), 0, stream, w_qkv, whi, wlo);
  hipLaunchKernelGGL(k_time_mlp, dim3(BB, 2), dim3(256), 0, stream,
                     timev, w_time, b_time, ln_gamma, cs, ct);
  hipLaunchKernelGGL(k_rowstats, dim3(BB * NN / 4), dim3(256), 0, stream, x, mean, rstd);
  hipLaunchKernelGGL(k_qkv_gemm, dim3(12, 512), dim3(256), 0, stream,
                     x, whi, wlo, mean, rstd, cs, ct, g_q, g_k, qhi, qlo, k_n, v_h);
  hipLaunchKernelGGL(k_kmax_part, dim3(64, 8), dim3(256), 0, stream, k_n, kmp);
  hipLaunchKernelGGL(k_kmax_red, dim3(16), dim3(256), 0, stream, kmp, km);
  hipLaunchKernelGGL(k_ctx_part, dim3(64, 8), dim3(256), 0, stream, k_n, v_h, km, Cp, Zp);
  hipLaunchKernelGGL(k_ctx_red, dim3(64), dim3(256), 0, stream, Cp, Zp, Cn);
  hipLaunchKernelGGL(k_mstack, dim3(64, 2), dim3(256), 0, stream, Cn, w_out, mhi, mlo);
  hipLaunchKernelGGL(k_out_gemm, dim3(4, 512), dim3(256), 0, stream, qhi, qlo, mhi, mlo, out);
  hipLaunchKernelGGL(k_ln_out, dim3(BB * NN / 4), dim3(256), 0, stream, out, ln_out_g);
}

// Round 6
// 1231.788 us; speedup vs baseline: 2.0089x; 1.1334x over previous
//
#include <hip/hip_runtime.h>
#include <cstdint>
#include <cmath>

#define BB   8
#define NN   8192
#define DIMC 512
#define HH   8
#define DHD  64
#define HIDC 512
#define TCDC 512

typedef __attribute__((ext_vector_type(8))) short bf16x8;
typedef __attribute__((ext_vector_type(4))) float f32x4;

// exact truncation split: v = hi + rem; lo = trunc-bf16(rem); |err| ~ 2^-17 |v|
__device__ inline void split2(float v, short* hi, short* lo) {
  unsigned u = __float_as_uint(v);
  float hf = __uint_as_float(u & 0xFFFF0000u);
  *hi = (short)(u >> 16);
  *lo = (short)(__float_as_uint(v - hf) >> 16);
}

__device__ inline void gload16(const void* g, void* l) {
  __builtin_amdgcn_global_load_lds(
      (const __attribute__((address_space(1))) unsigned*)g,
      (__attribute__((address_space(3))) unsigned*)l, 16, 0, 0);
}

// ---------------- K0: w_qkv -> bf16 hi/lo tiled image [nblk12][ktile16][kblk4][col128][kk8]
__global__ __launch_bounds__(256) void k_prep_w(
    const float* __restrict__ w, short* __restrict__ whi, short* __restrict__ wlo) {
  int nblk = blockIdx.x, ktile = blockIdx.y;
  int tid = threadIdx.x;
  size_t obase = ((size_t)(nblk * 16 + ktile)) * 4096;
  for (int i = tid; i < 4096; i += 256) {
    int kl = i >> 7, col = i & 127;
    float v = w[(size_t)(ktile * 32 + kl) * 1536 + nblk * 128 + col];
    short h, l; split2(v, &h, &l);
    size_t o = obase + ((size_t)((kl >> 3) * 128 + col)) * 8 + (kl & 7);
    whi[o] = h; wlo[o] = l;
  }
}

// ---------------- K1: t = silu(time) @ w_time + b_time -> cs, ct ----------------
__global__ __launch_bounds__(256) void k_time_mlp(
    const float* __restrict__ timev, const float* __restrict__ w_time,
    const float* __restrict__ b_time, const float* __restrict__ ln_gamma,
    float* __restrict__ cs, float* __restrict__ ct) {
  int b = blockIdx.x;
  int d = blockIdx.y * 256 + threadIdx.x;
  int tid = threadIdx.x;
  __shared__ float st[TCDC];
  for (int k = tid; k < TCDC; k += 256) {
    float v = timev[b * TCDC + k];
    st[k] = v / (1.f + __expf(-v));
  }
  __syncthreads();
  float accs = b_time[d];
  float acct = b_time[DIMC + d];
  for (int k = 0; k < TCDC; ++k) {
    float s = st[k];
    accs = fmaf(s, w_time[k * (2 * DIMC) + d], accs);
    acct = fmaf(s, w_time[k * (2 * DIMC) + DIMC + d], acct);
  }
  cs[b * DIMC + d] = ln_gamma[d] * (1.f + accs);
  ct[b * DIMC + d] = acct;
}

// ---------------- K2: per-row mean / rstd of x ----------------
__global__ __launch_bounds__(256) void k_rowstats(
    const float* __restrict__ x, float* __restrict__ mean, float* __restrict__ rstd) {
  int row = blockIdx.x * 4 + (threadIdx.x >> 6);
  int lane = threadIdx.x & 63;
  const float4* xr = (const float4*)(x + (size_t)row * DIMC);
  float s = 0.f, s2 = 0.f;
#pragma unroll
  for (int i = 0; i < 2; ++i) {
    float4 v = xr[lane + 64 * i];
    s  += v.x + v.y + v.z + v.w;
    s2 += v.x * v.x + v.y * v.y + v.z * v.z + v.w * v.w;
  }
#pragma unroll
  for (int m = 1; m < 64; m <<= 1) { s += __shfl_xor(s, m); s2 += __shfl_xor(s2, m); }
  float mu = s * (1.f / DIMC);
  float var = s2 * (1.f / DIMC) - mu * mu;
  if (lane == 0) { mean[row] = mu; rstd[row] = rsqrtf(var + 1e-5f); }
}

// ---------------- K2b: zero the Z accumulator (ws is poisoned 0xAA) ----------------
__global__ __launch_bounds__(256) void k_zero(float* __restrict__ Zg) {
  Zg[blockIdx.x * 256 + threadIdx.x] = 0.f;
}

// ---------------- K3: split-bf16 MFMA GEMM (LN+mod fused) with q/ek/v epilogue ----
// tile 128x128, BK=32, 4 waves (2x2), each wave 4x4 frags of 16x16x32. XCD-swizzled.
__global__ __launch_bounds__(256) void k_qkv_gemm(
    const float* __restrict__ x,
    const short* __restrict__ whi, const short* __restrict__ wlo,
    const float* __restrict__ mean, const float* __restrict__ rstd,
    const float* __restrict__ cs, const float* __restrict__ ct,
    const float* __restrict__ g_q, const float* __restrict__ g_k,
    short* __restrict__ qhi, short* __restrict__ qlo,
    short* __restrict__ ekhi, short* __restrict__ eklo,
    short* __restrict__ vhi, short* __restrict__ vlo,
    float* __restrict__ Zg) {
  __shared__ __align__(16) short As[2][4][128][8];   // [hi/lo][kblk][row^kblk][kk]
  __shared__ __align__(16) short Bs[2][4][128][8];   // [hi/lo][kblk][col][kk] linear
  int tid = threadIdx.x;
  int lane = tid & 63, wave = tid >> 6;
  int wr = wave >> 1, wc = wave & 1;
  int l15 = lane & 15, g = lane >> 4;
  // XCD swizzle: 12 blocks sharing an A-tile -> same XCD (6144 wgs, 768/XCD)
  int o = blockIdx.y * 12 + blockIdx.x;
  int tile = (o & 7) * 768 + (o >> 3);
  int mblk = tile / 12, nblk = tile - mblk * 12;
  int n0 = nblk * 128;
  int m0 = mblk * 128;
  int b = m0 >> 13;

  f32x4 acc[4][4];
#pragma unroll
  for (int mi = 0; mi < 4; ++mi)
#pragma unroll
    for (int ni = 0; ni < 4; ++ni) acc[mi][ni] = (f32x4){0.f, 0.f, 0.f, 0.f};

  int arow = tid >> 2;   // 0..63 (plus +64 in second half)
  int akc  = tid & 3;    // k-chunk of 8
  float mu0 = mean[m0 + arow],      rs0 = rstd[m0 + arow];
  float mu1 = mean[m0 + arow + 64], rs1 = rstd[m0 + arow + 64];

  for (int kt = 0; kt < 16; ++kt) {
    // ---- A staging: fp32 -> LN-mod -> split -> LDS (XOR swizzle row^kc) ----
    const float4 c1a = *(const float4*)(cs + b * DIMC + kt * 32 + akc * 8);
    const float4 c1b = *(const float4*)(cs + b * DIMC + kt * 32 + akc * 8 + 4);
    const float4 c2a = *(const float4*)(ct + b * DIMC + kt * 32 + akc * 8);
    const float4 c2b = *(const float4*)(ct + b * DIMC + kt * 32 + akc * 8 + 4);
#pragma unroll
    for (int half = 0; half < 2; ++half) {
      int row = arow + half * 64;
      float mu = half ? mu1 : mu0, rs = half ? rs1 : rs0;
      const float4* xa = (const float4*)(x + (size_t)(m0 + row) * DIMC + kt * 32 + akc * 8);
      float4 a0 = xa[0], a1 = xa[1];
      float vv[8];
      vv[0] = fmaf((a0.x - mu) * rs, c1a.x, c2a.x);
      vv[1] = fmaf((a0.y - mu) * rs, c1a.y, c2a.y);
      vv[2] = fmaf((a0.z - mu) * rs, c1a.z, c2a.z);
      vv[3] = fmaf((a0.w - mu) * rs, c1a.w, c2a.w);
      vv[4] = fmaf((a1.x - mu) * rs, c1b.x, c2b.x);
      vv[5] = fmaf((a1.y - mu) * rs, c1b.y, c2b.y);
      vv[6] = fmaf((a1.z - mu) * rs, c1b.z, c2b.z);
      vv[7] = fmaf((a1.w - mu) * rs, c1b.w, c2b.w);
      bf16x8 vh, vl;
#pragma unroll
      for (int i = 0; i < 8; ++i) {
        short hh, ll; split2(vv[i], &hh, &ll);
        vh[i] = hh; vl[i] = ll;
      }
      *(bf16x8*)&As[0][akc][row ^ akc][0] = vh;
      *(bf16x8*)&As[1][akc][row ^ akc][0] = vl;
    }
    // ---- B staging: contiguous image copy via global_load_lds ----
    size_t boff = ((size_t)(nblk * 16 + kt)) * 4096;
#pragma unroll
    for (int h = 0; h < 2; ++h) {
      const short* src = (h ? wlo : whi) + boff;
      short* dst = &Bs[h][0][0][0];
#pragma unroll
      for (int r = 0; r < 2; ++r) {
        int ci = (r * 4 + wave) * 64 + lane;
        gload16(src + (size_t)ci * 8, dst + (r * 4 + wave) * 512);
      }
    }
    __syncthreads();
    // ---- fragments + 48 MFMA ----
    bf16x8 ah[4], al[4], bh[4], bl[4];
#pragma unroll
    for (int i = 0; i < 4; ++i) {
      int row = wr * 64 + i * 16 + l15;
      ah[i] = *(const bf16x8*)&As[0][g][row ^ g][0];
      al[i] = *(const bf16x8*)&As[1][g][row ^ g][0];
      int col = wc * 64 + i * 16 + l15;
      bh[i] = *(const bf16x8*)&Bs[0][g][col][0];
      bl[i] = *(const bf16x8*)&Bs[1][g][col][0];
    }
#pragma unroll
    for (int mi = 0; mi < 4; ++mi)
#pragma unroll
      for (int ni = 0; ni < 4; ++ni) {
        acc[mi][ni] = __builtin_amdgcn_mfma_f32_16x16x32_bf16(ah[mi], bh[ni], acc[mi][ni], 0, 0, 0);
        acc[mi][ni] = __builtin_amdgcn_mfma_f32_16x16x32_bf16(ah[mi], bl[ni], acc[mi][ni], 0, 0, 0);
        acc[mi][ni] = __builtin_amdgcn_mfma_f32_16x16x32_bf16(al[mi], bh[ni], acc[mi][ni], 0, 0, 0);
      }
    __syncthreads();
  }

  // ---- epilogue ----
  int section = n0 >> 9;
  int h = ((n0 & 511) >> 6) + wc;   // head, uniform per wave
  int bh = b * HH + h;
  if (section == 2) {
    // V -> split-bf16 image (lives in d_out)
#pragma unroll
    for (int mi = 0; mi < 4; ++mi)
#pragma unroll
      for (int rg = 0; rg < 4; ++rg) {
        int grow = m0 + wr * 64 + mi * 16 + g * 4 + rg;
        int nrow = grow & (NN - 1);
        size_t tb = (((size_t)(bh * 8 + (nrow >> 10)) * 32 + ((nrow >> 5) & 31)) * 4 +
                     ((nrow >> 3) & 3)) * 512 + (nrow & 7);
#pragma unroll
        for (int ni = 0; ni < 4; ++ni) {
          short hh, ll; split2(acc[mi][ni][rg], &hh, &ll);
          size_t oo = tb + (size_t)(ni * 16 + l15) * 8;
          vhi[oo] = hh; vlo[oo] = ll;
        }
      }
  } else if (section == 0) {
    // Q -> rms-norm + softmax + scale -> split-bf16 image for K7
    float gq[4];
    int kt_[4], kb_[4], kk_[4];
#pragma unroll
    for (int ni = 0; ni < 4; ++ni) {
      int hid = h * 64 + ni * 16 + l15;
      gq[ni] = g_q[hid];
      kt_[ni] = hid >> 5; kb_[ni] = (hid >> 3) & 3; kk_[ni] = hid & 7;
    }
#pragma unroll
    for (int mi = 0; mi < 4; ++mi)
#pragma unroll
      for (int rg = 0; rg < 4; ++rg) {
        int grow = m0 + wr * 64 + mi * 16 + g * 4 + rg;
        float v[4];
#pragma unroll
        for (int ni = 0; ni < 4; ++ni) v[ni] = acc[mi][ni][rg];
        float ss = v[0] * v[0] + v[1] * v[1] + v[2] * v[2] + v[3] * v[3];
#pragma unroll
        for (int mk = 1; mk < 16; mk <<= 1) ss += __shfl_xor(ss, mk);
        float sc = 8.f / fmaxf(sqrtf(ss), 1e-12f);
#pragma unroll
        for (int ni = 0; ni < 4; ++ni) v[ni] *= sc * gq[ni];
        float mx = fmaxf(fmaxf(v[0], v[1]), fmaxf(v[2], v[3]));
#pragma unroll
        for (int mk = 1; mk < 16; mk <<= 1) mx = fmaxf(mx, __shfl_xor(mx, mk));
#pragma unroll
        for (int ni = 0; ni < 4; ++ni) v[ni] = __expf(v[ni] - mx);
        float se = v[0] + v[1] + v[2] + v[3];
#pragma unroll
        for (int mk = 1; mk < 16; mk <<= 1) se += __shfl_xor(se, mk);
        float inv = 0.125f / se;
        int mblk2 = grow >> 7, r = grow & 127;
#pragma unroll
        for (int ni = 0; ni < 4; ++ni) {
          short hh, ll; split2(v[ni] * inv, &hh, &ll);
          size_t oo = (((size_t)(mblk2 * 16 + kt_[ni]) * 4 + kb_[ni]) * 128 + r) * 8 + kk_[ni];
          qhi[oo] = hh; qlo[oo] = ll;
        }
      }
  } else {
    // K -> rms-norm -> ek = exp(k) split-bf16 image + Z atomics (no max needed:
    // |k| <= 8*|g_k| after rms-norm, exp stays in fp32 range)
    float gk[4];
#pragma unroll
    for (int ni = 0; ni < 4; ++ni) gk[ni] = g_k[h * 64 + ni * 16 + l15];
    float zp[4] = {0.f, 0.f, 0.f, 0.f};
#pragma unroll
    for (int mi = 0; mi < 4; ++mi)
#pragma unroll
      for (int rg = 0; rg < 4; ++rg) {
        int grow = m0 + wr * 64 + mi * 16 + g * 4 + rg;
        int nrow = grow & (NN - 1);
        float v[4];
#pragma unroll
        for (int ni = 0; ni < 4; ++ni) v[ni] = acc[mi][ni][rg];
        float ss = v[0] * v[0] + v[1] * v[1] + v[2] * v[2] + v[3] * v[3];
#pragma unroll
        for (int mk = 1; mk < 16; mk <<= 1) ss += __shfl_xor(ss, mk);
        float sc = 8.f / fmaxf(sqrtf(ss), 1e-12f);
        size_t tb = (((size_t)(bh * 8 + (nrow >> 10)) * 32 + ((nrow >> 5) & 31)) * 4 +
                     ((nrow >> 3) & 3)) * 512 + (nrow & 7);
#pragma unroll
        for (int ni = 0; ni < 4; ++ni) {
          float ekv = __expf(v[ni] * sc * gk[ni]);
          zp[ni] += ekv;
          short hh, ll; split2(ekv, &hh, &ll);
          size_t oo = tb + (size_t)(ni * 16 + l15) * 8;
          ekhi[oo] = hh; eklo[oo] = ll;
        }
      }
    // reduce zp over the 4 row-groups (g), then one atomic per (col)
#pragma unroll
    for (int ni = 0; ni < 4; ++ni) {
      zp[ni] += __shfl_xor(zp[ni], 16);
      zp[ni] += __shfl_xor(zp[ni], 32);
    }
    if (g == 0) {
#pragma unroll
      for (int ni = 0; ni < 4; ++ni)
        atomicAdd(&Zg[bh * 64 + ni * 16 + l15], zp[ni]);
    }
  }
}

// ---------------- K5: context C[bh][d][e] partials = sum_n ek[n,d] * v[n,e] -------
// MFMA GEMM M=64(d) N=64(e) K=1024 per (bh, kchunk); split-bf16 3-term.
__global__ __launch_bounds__(256) void k_ctx(
    const short* __restrict__ ekhi, const short* __restrict__ eklo,
    const short* __restrict__ vhi, const short* __restrict__ vlo,
    float* __restrict__ Cp) {
  __shared__ __align__(16) short As[2][4][64][8];
  __shared__ __align__(16) short Bs[2][4][64][8];
  int tid = threadIdx.x;
  int lane = tid & 63, wave = tid >> 6;
  int wr = wave >> 1, wc = wave & 1;
  int l15 = lane & 15, g = lane >> 4;
  int bh = blockIdx.x, kc = blockIdx.y;
  f32x4 acc[2][2];
#pragma unroll
  for (int mi = 0; mi < 2; ++mi)
#pragma unroll
    for (int nj = 0; nj < 2; ++nj) acc[mi][nj] = (f32x4){0.f, 0.f, 0.f, 0.f};

  size_t cbase = ((size_t)(bh * 8 + kc)) * 32 * 2048;
  int ci = wave * 64 + lane;
  for (int kt = 0; kt < 32; ++kt) {
    size_t tb = cbase + (size_t)kt * 2048 + (size_t)ci * 8;
    gload16(ekhi + tb, &As[0][0][0][0] + wave * 512);
    gload16(eklo + tb, &As[1][0][0][0] + wave * 512);
    gload16(vhi + tb, &Bs[0][0][0][0] + wave * 512);
    gload16(vlo + tb, &Bs[1][0][0][0] + wave * 512);
    __syncthreads();
    bf16x8 ah[2], al[2], bh_[2], bl_[2];
#pragma unroll
    for (int i = 0; i < 2; ++i) {
      int row = wr * 32 + i * 16 + l15;
      ah[i] = *(const bf16x8*)&As[0][g][row][0];
      al[i] = *(const bf16x8*)&As[1][g][row][0];
      int col = wc * 32 + i * 16 + l15;
      bh_[i] = *(const bf16x8*)&Bs[0][g][col][0];
      bl_[i] = *(const bf16x8*)&Bs[1][g][col][0];
    }
#pragma unroll
    for (int mi = 0; mi < 2; ++mi)
#pragma unroll
      for (int nj = 0; nj < 2; ++nj) {
        acc[mi][nj] = __builtin_amdgcn_mfma_f32_16x16x32_bf16(ah[mi], bh_[nj], acc[mi][nj], 0, 0, 0);
        acc[mi][nj] = __builtin_amdgcn_mfma_f32_16x16x32_bf16(ah[mi], bl_[nj], acc[mi][nj], 0, 0, 0);
        acc[mi][nj] = __builtin_amdgcn_mfma_f32_16x16x32_bf16(al[mi], bh_[nj], acc[mi][nj], 0, 0, 0);
      }
    __syncthreads();
  }
  float* cp = Cp + ((size_t)(bh * 8 + kc)) * 4096;
#pragma unroll
  for (int mi = 0; mi < 2; ++mi)
#pragma unroll
    for (int rg = 0; rg < 4; ++rg) {
      int d = wr * 32 + mi * 16 + g * 4 + rg;
#pragma unroll
      for (int nj = 0; nj < 2; ++nj)
        cp[d * 64 + wc * 32 + nj * 16 + l15] = acc[mi][nj][rg];
    }
}

// ---------------- K6a: reduce partials, normalize by Z ----------------
__global__ __launch_bounds__(256) void k_ctx_red(
    const float* __restrict__ Cp, const float* __restrict__ Zg, float* __restrict__ Cn) {
  int bh = blockIdx.x;
  int tid = threadIdx.x;
  __shared__ float zs[64];
  if (tid < 64) zs[tid] = 1.f / Zg[bh * 64 + tid];
  __syncthreads();
  for (int i = tid; i < DHD * DHD; i += 256) {
    float s = 0.f;
    for (int c = 0; c < 8; ++c) s += Cp[(size_t)(bh * 8 + c) * 4096 + i];
    Cn[(size_t)bh * 4096 + i] = s * zs[i >> 6];
  }
}

// ---------------- K6b: Ms image = C @ w_out (bf16 hi/lo, tiled for K7) ----------------
__global__ __launch_bounds__(256) void k_mstack(
    const float* __restrict__ Cn, const float* __restrict__ w_out,
    short* __restrict__ mhi, short* __restrict__ mlo) {
  int bh = blockIdx.x;
  int b = bh >> 3, h = bh & 7;
  int j0 = blockIdx.y * 256;
  int tid = threadIdx.x;
  int d = tid & 63, jg = tid >> 6;
  __shared__ float Cs[64][65];
  for (int i = tid; i < 4096; i += 256) Cs[i >> 6][i & 63] = Cn[(size_t)bh * 4096 + i];
  __syncthreads();
  int ktile = h * 2 + (d >> 5), kblk = (d >> 3) & 3, kk = d & 7;
  for (int jj = 0; jj < 64; ++jj) {
    int j = j0 + jg * 64 + jj;
    float s = 0.f;
#pragma unroll 16
    for (int e = 0; e < 64; ++e) s = fmaf(Cs[d][e], w_out[(size_t)(h * 64 + e) * DIMC + j], s);
    short hh, ll; split2(s, &hh, &ll);
    size_t o = ((((size_t)(b * 4 + (j >> 7)) * 16 + ktile) * 4 + kblk) * 128 + (j & 127)) * 8 + kk;
    mhi[o] = hh; mlo[o] = ll;
  }
}

// ---------------- K7: out = qs @ Ms[b] — both operands via global_load_lds ----------------
__global__ __launch_bounds__(256) void k_out_gemm(
    const short* __restrict__ qhi, const short* __restrict__ qlo,
    const short* __restrict__ mhi, const short* __restrict__ mlo,
    float* __restrict__ out) {
  __shared__ __align__(16) short As[2][4][128][8];
  __shared__ __align__(16) short Bs[2][4][128][8];
  int tid = threadIdx.x;
  int lane = tid & 63, wave = tid >> 6;
  int wr = wave >> 1, wc = wave & 1;
  int l15 = lane & 15, g = lane >> 4;
  // XCD swizzle: 4 blocks sharing an A-tile -> same XCD (2048 wgs, 256/XCD)
  int o = blockIdx.y * 4 + blockIdx.x;
  int tile = (o & 7) * 256 + (o >> 3);
  int mblk = tile >> 2, nblk = tile & 3;
  int n0 = nblk * 128, m0 = mblk * 128;
  int b = m0 >> 13;

  f32x4 acc[4][4];
#pragma unroll
  for (int mi = 0; mi < 4; ++mi)
#pragma unroll
    for (int ni = 0; ni < 4; ++ni) acc[mi][ni] = (f32x4){0.f, 0.f, 0.f, 0.f};

  for (int kt = 0; kt < 16; ++kt) {
    size_t aoff = ((size_t)(mblk * 16 + kt)) * 4096;
    size_t boff = ((size_t)((b * 4 + nblk) * 16 + kt)) * 4096;
#pragma unroll
    for (int h = 0; h < 2; ++h) {
      const short* asrc = (h ? qlo : qhi) + aoff;
      const short* bsrc = (h ? mlo : mhi) + boff;
#pragma unroll
      for (int r = 0; r < 2; ++r) {
        int ci = (r * 4 + wave) * 64 + lane;
        gload16(asrc + (size_t)ci * 8, &As[h][0][0][0] + (r * 4 + wave) * 512);
        gload16(bsrc + (size_t)ci * 8, &Bs[h][0][0][0] + (r * 4 + wave) * 512);
      }
    }
    __syncthreads();
    bf16x8 ah[4], al[4], bh[4], bl[4];
#pragma unroll
    for (int i = 0; i < 4; ++i) {
      int row = wr * 64 + i * 16 + l15;
      ah[i] = *(const bf16x8*)&As[0][g][row][0];
      al[i] = *(const bf16x8*)&As[1][g][row][0];
      int col = wc * 64 + i * 16 + l15;
      bh[i] = *(const bf16x8*)&Bs[0][g][col][0];
      bl[i] = *(const bf16x8*)&Bs[1][g][col][0];
    }
#pragma unroll
    for (int mi = 0; mi < 4; ++mi)
#pragma unroll
      for (int ni = 0; ni < 4; ++ni) {
        acc[mi][ni] = __builtin_amdgcn_mfma_f32_16x16x32_bf16(ah[mi], bh[ni], acc[mi][ni], 0, 0, 0);
        acc[mi][ni] = __builtin_amdgcn_mfma_f32_16x16x32_bf16(ah[mi], bl[ni], acc[mi][ni], 0, 0, 0);
        acc[mi][ni] = __builtin_amdgcn_mfma_f32_16x16x32_bf16(al[mi], bh[ni], acc[mi][ni], 0, 0, 0);
      }
    __syncthreads();
  }
#pragma unroll
  for (int mi = 0; mi < 4; ++mi)
#pragma unroll
    for (int rg = 0; rg < 4; ++rg) {
      int grow = m0 + wr * 64 + mi * 16 + g * 4 + rg;
#pragma unroll
      for (int ni = 0; ni < 4; ++ni)
        out[(size_t)grow * DIMC + n0 + wc * 64 + ni * 16 + l15] = acc[mi][ni][rg];
    }
}

// ---------------- K8: in-place final LayerNorm on d_out ----------------
__global__ __launch_bounds__(256) void k_ln_out(
    float* __restrict__ y, const float* __restrict__ gamma) {
  int row = blockIdx.x * 4 + (threadIdx.x >> 6);
  int lane = threadIdx.x & 63;
  float4* yr = (float4*)(y + (size_t)row * DIMC);
  float4 v0 = yr[lane], v1 = yr[lane + 64];
  float s = v0.x + v0.y + v0.z + v0.w + v1.x + v1.y + v1.z + v1.w;
  float s2 = v0.x * v0.x + v0.y * v0.y + v0.z * v0.z + v0.w * v0.w +
             v1.x * v1.x + v1.y * v1.y + v1.z * v1.z + v1.w * v1.w;
#pragma unroll
  for (int m = 1; m < 64; m <<= 1) { s += __shfl_xor(s, m); s2 += __shfl_xor(s2, m); }
  float mu = s * (1.f / DIMC);
  float rs = rsqrtf(s2 * (1.f / DIMC) - mu * mu + 1e-5f);
  const float4* gp = (const float4*)gamma;
  float4 g0 = gp[lane], g1 = gp[lane + 64];
  v0.x = (v0.x - mu) * rs * g0.x; v0.y = (v0.y - mu) * rs * g0.y;
  v0.z = (v0.z - mu) * rs * g0.z; v0.w = (v0.w - mu) * rs * g0.w;
  v1.x = (v1.x - mu) * rs * g1.x; v1.y = (v1.y - mu) * rs * g1.y;
  v1.z = (v1.z - mu) * rs * g1.z; v1.w = (v1.w - mu) * rs * g1.w;
  yr[lane] = v0; yr[lane + 64] = v1;
}

extern "C" void kernel_launch(void* const* d_in, const int* in_sizes, int n_in,
                              void* d_out, int out_size, void* d_ws, size_t ws_size,
                              hipStream_t stream) {
  (void)in_sizes; (void)n_in; (void)out_size; (void)ws_size;
  const float* x        = (const float*)d_in[0];
  const float* timev    = (const float*)d_in[1];
  const float* ln_gamma = (const float*)d_in[2];
  const float* w_time   = (const float*)d_in[3];
  const float* b_time   = (const float*)d_in[4];
  const float* w_qkv    = (const float*)d_in[5];
  const float* g_q      = (const float*)d_in[6];
  const float* g_k      = (const float*)d_in[7];
  const float* w_out    = (const float*)d_in[8];
  const float* ln_out_g = (const float*)d_in[9];
  float* out = (float*)d_out;

  // workspace layout (~282 MB, within the proven footprint)
  float* cs   = (float*)d_ws;          // 4096
  float* ct   = cs + 4096;             // 4096
  float* mean = ct + 4096;             // 65536
  float* rstd = mean + 65536;          // 65536
  float* Zg   = rstd + 65536;          // 4096
  float* Cp   = Zg + 4096;             // 2097152 (8 MB)
  float* Cn   = Cp + 2097152;          // 262144
  short* whi  = (short*)(Cn + 262144); // 786432
  short* wlo  = whi + 786432;
  short* qhi  = wlo + 786432;          // 33554432 shorts (67 MB)
  short* qlo  = qhi + 33554432;
  short* ekhi = qlo + 33554432;        // 33554432 shorts
  short* eklo = ekhi + 33554432;
  short* mhi  = ekhi;                  // alias: ek dead after k_ctx, Ms written by k_mstack
  short* mlo  = ekhi + 2097152;
  short* vhi  = (short*)d_out;         // V image lives in d_out until K7 overwrites it
  short* vlo  = vhi + 33554432;

  hipLaunchKernelGGL(k_prep_w, dim3(12, 16), dim3(256), 0, stream, w_qkv, whi, wlo);
  hipLaunchKernelGGL(k_time_mlp, dim3(BB, 2), dim3(256), 0, stream,
                     timev, w_time, b_time, ln_gamma, cs, ct);
  hipLaunchKernelGGL(k_rowstats, dim3(BB * NN / 4), dim3(256), 0, stream, x, mean, rstd);
  hipLaunchKernelGGL(k_zero, dim3(16), dim3(256), 0, stream, Zg);
  hipLaunchKernelGGL(k_qkv_gemm, dim3(12, 512), dim3(256), 0, stream,
                     x, whi, wlo, mean, rstd, cs, ct, g_q, g_k,
                     qhi, qlo, ekhi, eklo, vhi, vlo, Zg);
  hipLaunchKernelGGL(k_ctx, dim3(64, 8), dim3(256), 0, stream, ekhi, eklo, vhi, vlo, Cp);
  hipLaunchKernelGGL(k_ctx_red, dim3(64), dim3(256), 0, stream, Cp, Zg, Cn);
  hipLaunchKernelGGL(k_mstack, dim3(64, 2), dim3(256), 0, stream, Cn, w_out, mhi, mlo);
  hipLaunchKernelGGL(k_out_gemm, dim3(4, 512), dim3(256), 0, stream, qhi, qlo, mhi, mlo, out);
  hipLaunchKernelGGL(k_ln_out, dim3(BB * NN / 4), dim3(256), 0, stream, out, ln_out_g);
}